// Round 1
// baseline (2673.916 us; speedup 1.0000x reference)
//
#include <hip/hip_runtime.h>
#include <hip/hip_bf16.h>

// Problem dims
#define BB    16
#define LL    4096
#define DIN   100
#define HD    256
#define NN    32       // complex states per channel
#define DHID  512
#define DOUT  100
#define MROWS (BB*LL)  // 65536

// ws layout (float offsets)
#define OFF_WRE   0
#define OFF_WIM   8192
#define OFF_KRE   16384
#define OFF_KIM   24576
#define OFF_WENC  32768                 // [k=100][h=256]
#define OFF_ENCB  58368
#define OFF_DSK   58624
#define OFF_LNG   58880
#define OFF_LNB   59136
#define OFF_W1T   59392                 // [k=256][j=512]
#define OFF_B1    190464
#define OFF_W2T   190976                // [k=512][j=128 padded]
#define OFF_B2    256512                // 128 padded
#define OFF_U     262144                // U fp32 (B,L,H) 16777216 ; later reused as G bf16 (B,L,512)
#define OFF_H1    (262144+16777216)     // H1 fp32 (B,L,H), LN done in place -> T
// total floats = 33816576  (~135.3 MB of ws)

static __device__ __forceinline__ int probe_bf16(const void* lng) {
    return ((const unsigned int*)lng)[0] != 0x3f800000u;
}
static __device__ __forceinline__ float ldin(const void* p, long i, int isbf) {
    return isbf ? __bfloat162float(((const __hip_bfloat16*)p)[i]) : ((const float*)p)[i];
}
static __device__ __forceinline__ void stout(void* p, long i, float v, int isbf) {
    if (isbf) ((__hip_bfloat16*)p)[i] = __float2bfloat16(v);
    else      ((float*)p)[i] = v;
}
static __device__ __forceinline__ float gelu_exact(float x) {
    return 0.5f * x * (1.0f + erff(x * 0.70710678118654752f));
}

// ---------------- K0: derived SSM params + weight convert/transpose ----------------
__global__ __launch_bounds__(256) void k_prep(
    const void* encw, const void* encb, const void* logdt, const void* loga,
    const void* aim, const void* bre, const void* bim, const void* cre,
    const void* cim, const void* dsk, const void* lng, const void* lnb,
    const void* w1, const void* b1, const void* w2, const void* b2, float* ws)
{
    const int isbf = probe_bf16(lng);
    const int total = 8192 + 25600 + 256*4 + 131072 + 512 + 65536 + 128;
    for (int idx = blockIdx.x * blockDim.x + threadIdx.x; idx < total;
         idx += gridDim.x * blockDim.x) {
        int i = idx;
        if (i < 8192) {
            int h = i >> 5;
            float dt  = expf(ldin(logdt, h, isbf));
            float Are = -expf(ldin(loga, i, isbf));
            float Aim = ldin(aim, i, isbf);
            float er  = expf(dt * Are);
            float sv, cv; sincosf(dt * Aim, &sv, &cv);
            float wre = er * cv, wim = er * sv;
            float Bre = ldin(bre, i, isbf), Bim = ldin(bim, i, isbf);
            float Cre = ldin(cre, i, isbf), Cim = ldin(cim, i, isbf);
            float C0re = Bre*Cre - Bim*Cim;
            float C0im = Bre*Cim + Bim*Cre;
            // Z = (w-1)/A
            float inv = 1.0f / (Are*Are + Aim*Aim);
            float nre = wre - 1.0f, nim = wim;
            float Zre = (nre*Are + nim*Aim) * inv;
            float Zim = (nim*Are - nre*Aim) * inv;
            float Cpre = C0re*Zre - C0im*Zim;
            float Cpim = C0re*Zim + C0im*Zre;
            ws[OFF_WRE + i] = wre;  ws[OFF_WIM + i] = wim;
            ws[OFF_KRE + i] = 2.0f * Cpre;  ws[OFF_KIM + i] = -2.0f * Cpim;
        } else if ((i -= 8192) < 25600) {          // enc_w (256,100) -> [k][h]
            int h = i % 256, k = i / 256;
            ws[OFF_WENC + k*256 + h] = ldin(encw, (long)h*100 + k, isbf);
        } else if ((i -= 25600) < 256) {
            ws[OFF_ENCB + i] = ldin(encb, i, isbf);
        } else if ((i -= 256) < 256) {
            ws[OFF_DSK + i] = ldin(dsk, i, isbf);
        } else if ((i -= 256) < 256) {
            ws[OFF_LNG + i] = ldin(lng, i, isbf);
        } else if ((i -= 256) < 256) {
            ws[OFF_LNB + i] = ldin(lnb, i, isbf);
        } else if ((i -= 256) < 131072) {          // dec1_w (512,256) -> [k][j]
            int j = i & 511, k = i >> 9;
            ws[OFF_W1T + i] = ldin(w1, (long)j*256 + k, isbf);
        } else if ((i -= 131072) < 512) {
            ws[OFF_B1 + i] = ldin(b1, i, isbf);
        } else if ((i -= 512) < 65536) {           // dec2_w (100,512) -> [k][j pad 128]
            int j = i & 127, k = i >> 7;
            ws[OFF_W2T + i] = (j < 100) ? ldin(w2, (long)j*512 + k, isbf) : 0.0f;
        } else if ((i -= 65536) < 128) {
            ws[OFF_B2 + i] = (i < 100) ? ldin(b2, i, isbf) : 0.0f;
        }
    }
}

// ---------------- K1: encoder GEMM  U[M,256] = x[M,100] @ WencT + b ----------------
__global__ __launch_bounds__(256) void k_enc(const void* x, const void* lng, float* ws)
{
    const int isbf = probe_bf16(lng);
    __shared__ __align__(16) float xs[50*68];
    __shared__ __align__(16) float wsb[50*68];
    int bid = blockIdx.x;
    int rt = bid >> 2, ct = bid & 3;
    long row0 = (long)rt * 64;
    int c0 = ct * 64;
    int t = threadIdx.x, tx = t & 15, ty = t >> 4;
    const float* Wt = ws + OFF_WENC;
    float acc[4][4] = {};
    for (int kc = 0; kc < 2; ++kc) {
        int k0 = kc * 50;
        for (int idx = t; idx < 64*50; idx += 256) {
            int k = idx % 50, r = idx / 50;
            xs[k*68 + r] = ldin(x, (row0 + r)*100 + k0 + k, isbf);
        }
        for (int idx = t; idx < 50*64; idx += 256) {
            int c = idx & 63, k = idx >> 6;
            wsb[k*68 + c] = Wt[(k0 + k)*256 + c0 + c];
        }
        __syncthreads();
        #pragma unroll 5
        for (int k = 0; k < 50; ++k) {
            float4 av = *(const float4*)&xs[k*68 + 4*ty];
            float4 bv = *(const float4*)&wsb[k*68 + 4*tx];
            float a4[4] = {av.x, av.y, av.z, av.w};
            float b4[4] = {bv.x, bv.y, bv.z, bv.w};
            #pragma unroll
            for (int r = 0; r < 4; ++r)
                #pragma unroll
                for (int c = 0; c < 4; ++c)
                    acc[r][c] = fmaf(a4[r], b4[c], acc[r][c]);
        }
        __syncthreads();
    }
    const float* eb = ws + OFF_ENCB;
    float* U = ws + OFF_U;
    #pragma unroll
    for (int r = 0; r < 4; ++r)
        #pragma unroll
        for (int c = 0; c < 4; ++c) {
            long row = row0 + 4*ty + r;
            int col = c0 + 4*tx + c;
            U[row*256 + col] = acc[r][c] + eb[col];
        }
}

// ---------------- K2: diagonal SSM scan + Dskip + GELU + residual ----------------
// lane = (h within group of 8, n); 512 blocks x 256 threads = 2048 waves
__global__ __launch_bounds__(256) void k_scan(float* ws)
{
    int bid = blockIdx.x;
    int b = bid >> 5, hg = bid & 31;
    int t = threadIdx.x;
    int h = hg*8 + (t >> 5);
    int n = t & 31;
    int i = h*32 + n;
    float wre = ws[OFF_WRE + i], wim = ws[OFF_WIM + i];
    float kre = ws[OFF_KRE + i], kim = ws[OFF_KIM + i];
    float D = ws[OFF_DSK + h];
    const float* U  = ws + OFF_U  + (long)b*LL*256 + h;
    float*       H1 = ws + OFF_H1 + (long)b*LL*256 + h;
    float sre = 0.0f, sim = 0.0f;
    #pragma unroll 4
    for (int l = 0; l < LL; ++l) {
        float u = U[(long)l * 256];
        float nsre = fmaf(wre, sre, fmaf(-wim, sim, u));
        float nsim = fmaf(wim, sre, wre * sim);
        sre = nsre; sim = nsim;
        float part = fmaf(kre, sre, kim * sim);
        part += __shfl_xor(part, 1);
        part += __shfl_xor(part, 2);
        part += __shfl_xor(part, 4);
        part += __shfl_xor(part, 8);
        part += __shfl_xor(part, 16);
        if (n == 0) {
            float val = fmaf(D, u, part);
            H1[(long)l * 256] = gelu_exact(val) + u;
        }
    }
}

// ---------------- K3: LayerNorm over H (in place H1 -> T) ----------------
__global__ __launch_bounds__(256) void k_ln(float* ws)
{
    long row = blockIdx.x;
    float* H1 = ws + OFF_H1 + row * 256;
    int t = threadIdx.x;
    float v = H1[t];
    __shared__ float red[4];
    float s = v;
    s += __shfl_xor(s, 1);  s += __shfl_xor(s, 2);  s += __shfl_xor(s, 4);
    s += __shfl_xor(s, 8);  s += __shfl_xor(s, 16); s += __shfl_xor(s, 32);
    if ((t & 63) == 0) red[t >> 6] = s;
    __syncthreads();
    float mean = (red[0] + red[1] + red[2] + red[3]) * (1.0f/256.0f);
    __syncthreads();
    float d = v - mean;
    float q = d * d;
    q += __shfl_xor(q, 1);  q += __shfl_xor(q, 2);  q += __shfl_xor(q, 4);
    q += __shfl_xor(q, 8);  q += __shfl_xor(q, 16); q += __shfl_xor(q, 32);
    if ((t & 63) == 0) red[t >> 6] = q;
    __syncthreads();
    float var = (red[0] + red[1] + red[2] + red[3]) * (1.0f/256.0f);
    float rs = rsqrtf(var + 1e-5f);
    H1[t] = d * rs * ws[OFF_LNG + t] + ws[OFF_LNB + t];
}

// ---------------- K4: dec1 GEMM + GELU -> G (bf16, reuses U slot) ----------------
__global__ __launch_bounds__(256) void k_dec1(float* ws)
{
    __shared__ __align__(16) float as[64*68];
    __shared__ __align__(16) float bs[64*68];
    int bid = blockIdx.x;            // 1024 row tiles x 8 col tiles
    int rt = bid >> 3, ct = bid & 7;
    long row0 = (long)rt * 64;
    int c0 = ct * 64;
    int t = threadIdx.x, tx = t & 15, ty = t >> 4;
    const float* T  = ws + OFF_H1;
    const float* W1 = ws + OFF_W1T;
    float acc[4][4] = {};
    for (int kc = 0; kc < 4; ++kc) {
        int k0 = kc * 64;
        for (int idx = t; idx < 4096; idx += 256) {
            int k = idx & 63, r = idx >> 6;
            as[k*68 + r] = T[(row0 + r)*256 + k0 + k];
        }
        for (int idx = t; idx < 4096; idx += 256) {
            int c = idx & 63, k = idx >> 6;
            bs[k*68 + c] = W1[(k0 + k)*512 + c0 + c];
        }
        __syncthreads();
        #pragma unroll 8
        for (int k = 0; k < 64; ++k) {
            float4 av = *(const float4*)&as[k*68 + 4*ty];
            float4 bv = *(const float4*)&bs[k*68 + 4*tx];
            float a4[4] = {av.x, av.y, av.z, av.w};
            float b4[4] = {bv.x, bv.y, bv.z, bv.w};
            #pragma unroll
            for (int r = 0; r < 4; ++r)
                #pragma unroll
                for (int c = 0; c < 4; ++c)
                    acc[r][c] = fmaf(a4[r], b4[c], acc[r][c]);
        }
        __syncthreads();
    }
    const float* b1 = ws + OFF_B1;
    __hip_bfloat16* G = (__hip_bfloat16*)(ws + OFF_U);
    #pragma unroll
    for (int r = 0; r < 4; ++r)
        #pragma unroll
        for (int c = 0; c < 4; ++c) {
            long row = row0 + 4*ty + r;
            int col = c0 + 4*tx + c;
            float g = gelu_exact(acc[r][c] + b1[col]);
            G[row*512 + col] = __float2bfloat16(g);
        }
}

// ---------------- K5: dec2 GEMM + bias -> d_out ----------------
__global__ __launch_bounds__(256) void k_dec2(float* ws, void* out, const void* lng)
{
    const int isbf = probe_bf16(lng);
    __shared__ __align__(16) float as[64*68];
    __shared__ __align__(16) float bs[64*132];
    int rt = blockIdx.x;             // 1024 row tiles, single col tile (128 >= 100)
    long row0 = (long)rt * 64;
    int t = threadIdx.x, tx = t & 15, ty = t >> 4;
    const __hip_bfloat16* G = (const __hip_bfloat16*)(ws + OFF_U);
    const float* W2 = ws + OFF_W2T;
    float acc[4][8] = {};
    for (int kc = 0; kc < 8; ++kc) {
        int k0 = kc * 64;
        for (int idx = t; idx < 4096; idx += 256) {
            int k = idx & 63, r = idx >> 6;
            as[k*68 + r] = __bfloat162float(G[(row0 + r)*512 + k0 + k]);
        }
        for (int idx = t; idx < 64*128; idx += 256) {
            int c = idx & 127, k = idx >> 7;
            bs[k*132 + c] = W2[(k0 + k)*128 + c];
        }
        __syncthreads();
        #pragma unroll 4
        for (int k = 0; k < 64; ++k) {
            float4 av = *(const float4*)&as[k*68 + 4*ty];
            float4 b0 = *(const float4*)&bs[k*132 + 8*tx];
            float4 b1v = *(const float4*)&bs[k*132 + 8*tx + 4];
            float a4[4] = {av.x, av.y, av.z, av.w};
            float b8[8] = {b0.x, b0.y, b0.z, b0.w, b1v.x, b1v.y, b1v.z, b1v.w};
            #pragma unroll
            for (int r = 0; r < 4; ++r)
                #pragma unroll
                for (int c = 0; c < 8; ++c)
                    acc[r][c] = fmaf(a4[r], b8[c], acc[r][c]);
        }
        __syncthreads();
    }
    const float* b2 = ws + OFF_B2;
    #pragma unroll
    for (int r = 0; r < 4; ++r)
        #pragma unroll
        for (int c = 0; c < 8; ++c) {
            int col = 8*tx + c;
            if (col < 100) {
                long row = row0 + 4*ty + r;
                stout(out, row*100 + col, acc[r][c] + b2[col], isbf);
            }
        }
}

extern "C" void kernel_launch(void* const* d_in, const int* in_sizes, int n_in,
                              void* d_out, int out_size, void* d_ws, size_t ws_size,
                              hipStream_t stream)
{
    float* ws = (float*)d_ws;
    k_prep<<<512, 256, 0, stream>>>(d_in[1], d_in[2], d_in[3], d_in[4], d_in[5],
                                    d_in[6], d_in[7], d_in[8], d_in[9], d_in[10],
                                    d_in[11], d_in[12], d_in[13], d_in[14],
                                    d_in[15], d_in[16], ws);
    k_enc<<<4096, 256, 0, stream>>>(d_in[0], d_in[11], ws);
    k_scan<<<512, 256, 0, stream>>>(ws);
    k_ln<<<65536, 256, 0, stream>>>(ws);
    k_dec1<<<8192, 256, 0, stream>>>(ws);
    k_dec2<<<1024, 256, 0, stream>>>(ws, d_out, d_in[11]);
}

// Round 2
// 811.452 us; speedup vs baseline: 3.2952x; 3.2952x over previous
//
#include <hip/hip_runtime.h>
#include <hip/hip_bf16.h>

// Problem dims
#define BB    16
#define LL    4096
#define DIN   100
#define HD    256
#define NN    32       // complex states per channel
#define DHID  512
#define DOUT  100
#define MROWS (BB*LL)  // 65536
#define CH    128      // scan chunk length
#define CC    32       // chunks per sequence (CH*CC == LL)

// ws layout (float offsets)
#define OFF_WRE   0
#define OFF_WIM   8192
#define OFF_KRE   16384
#define OFF_KIM   24576
#define OFF_WCHR  32768                 // w^CH real
#define OFF_WCHI  40960                 // w^CH imag
#define OFF_WENC  49152                 // [k=100][h=256]
#define OFF_ENCB  74752
#define OFF_DSK   75008
#define OFF_LNG   75264
#define OFF_LNB   75520
#define OFF_W1T   75776                 // [k=256][j=512]
#define OFF_B1    206848
#define OFF_W2T   207360                // [k=512][j=128 padded]
#define OFF_B2    272896                // 128 padded
#define OFF_U     273024                // U fp32 (B,L,H) 16777216 ; later reused as G bf16 (B,L,512)
#define OFF_H1    (273024+16777216)     // H1 fp32 (B,L,H); chunk states overlaid per-chunk pre-pass3
// total floats = 33827456  (~135.3 MB of ws)

static __device__ __forceinline__ int probe_bf16(const void* lng) {
    return ((const unsigned int*)lng)[0] != 0x3f800000u;
}
static __device__ __forceinline__ float ldin(const void* p, long i, int isbf) {
    return isbf ? __bfloat162float(((const __hip_bfloat16*)p)[i]) : ((const float*)p)[i];
}
static __device__ __forceinline__ void stout(void* p, long i, float v, int isbf) {
    if (isbf) ((__hip_bfloat16*)p)[i] = __float2bfloat16(v);
    else      ((float*)p)[i] = v;
}
static __device__ __forceinline__ float gelu_exact(float x) {
    return 0.5f * x * (1.0f + erff(x * 0.70710678118654752f));
}

// ---------------- K0: derived SSM params + weight convert/transpose ----------------
__global__ __launch_bounds__(256) void k_prep(
    const void* encw, const void* encb, const void* logdt, const void* loga,
    const void* aim, const void* bre, const void* bim, const void* cre,
    const void* cim, const void* dsk, const void* lng, const void* lnb,
    const void* w1, const void* b1, const void* w2, const void* b2, float* ws)
{
    const int isbf = probe_bf16(lng);
    const int total = 8192 + 25600 + 256*4 + 131072 + 512 + 65536 + 128;
    for (int idx = blockIdx.x * blockDim.x + threadIdx.x; idx < total;
         idx += gridDim.x * blockDim.x) {
        int i = idx;
        if (i < 8192) {
            int h = i >> 5;
            float dt  = expf(ldin(logdt, h, isbf));
            float Are = -expf(ldin(loga, i, isbf));
            float Aim = ldin(aim, i, isbf);
            float er  = expf(dt * Are);
            float sv, cv; sincosf(dt * Aim, &sv, &cv);
            float wre = er * cv, wim = er * sv;
            float Bre = ldin(bre, i, isbf), Bim = ldin(bim, i, isbf);
            float Cre = ldin(cre, i, isbf), Cim = ldin(cim, i, isbf);
            float C0re = Bre*Cre - Bim*Cim;
            float C0im = Bre*Cim + Bim*Cre;
            // Z = (w-1)/A
            float inv = 1.0f / (Are*Are + Aim*Aim);
            float nre = wre - 1.0f, nim = wim;
            float Zre = (nre*Are + nim*Aim) * inv;
            float Zim = (nim*Are - nre*Aim) * inv;
            float Cpre = C0re*Zre - C0im*Zim;
            float Cpim = C0re*Zim + C0im*Zre;
            ws[OFF_WRE + i] = wre;  ws[OFF_WIM + i] = wim;
            ws[OFF_KRE + i] = 2.0f * Cpre;  ws[OFF_KIM + i] = -2.0f * Cpim;
            // w^CH via 7 squarings (CH = 128)
            float ar = wre, ai = wim;
            #pragma unroll
            for (int q = 0; q < 7; ++q) {
                float nr2 = ar*ar - ai*ai;
                float ni2 = 2.0f*ar*ai;
                ar = nr2; ai = ni2;
            }
            ws[OFF_WCHR + i] = ar;  ws[OFF_WCHI + i] = ai;
        } else if ((i -= 8192) < 25600) {          // enc_w (256,100) -> [k][h]
            int h = i % 256, k = i / 256;
            ws[OFF_WENC + k*256 + h] = ldin(encw, (long)h*100 + k, isbf);
        } else if ((i -= 25600) < 256) {
            ws[OFF_ENCB + i] = ldin(encb, i, isbf);
        } else if ((i -= 256) < 256) {
            ws[OFF_DSK + i] = ldin(dsk, i, isbf);
        } else if ((i -= 256) < 256) {
            ws[OFF_LNG + i] = ldin(lng, i, isbf);
        } else if ((i -= 256) < 256) {
            ws[OFF_LNB + i] = ldin(lnb, i, isbf);
        } else if ((i -= 256) < 131072) {          // dec1_w (512,256) -> [k][j]
            int j = i & 511, k = i >> 9;
            ws[OFF_W1T + i] = ldin(w1, (long)j*256 + k, isbf);
        } else if ((i -= 131072) < 512) {
            ws[OFF_B1 + i] = ldin(b1, i, isbf);
        } else if ((i -= 512) < 65536) {           // dec2_w (100,512) -> [k][j pad 128]
            int j = i & 127, k = i >> 7;
            ws[OFF_W2T + i] = (j < 100) ? ldin(w2, (long)j*512 + k, isbf) : 0.0f;
        } else if ((i -= 65536) < 128) {
            ws[OFF_B2 + i] = (i < 100) ? ldin(b2, i, isbf) : 0.0f;
        }
    }
}

// ---------------- K1: encoder GEMM  U[M,256] = x[M,100] @ WencT + b ----------------
__global__ __launch_bounds__(256) void k_enc(const void* x, const void* lng, float* ws)
{
    const int isbf = probe_bf16(lng);
    __shared__ __align__(16) float xs[50*68];
    __shared__ __align__(16) float wsb[50*68];
    int bid = blockIdx.x;
    int rt = bid >> 2, ct = bid & 3;
    long row0 = (long)rt * 64;
    int c0 = ct * 64;
    int t = threadIdx.x, tx = t & 15, ty = t >> 4;
    const float* Wt = ws + OFF_WENC;
    float acc[4][4] = {};
    for (int kc = 0; kc < 2; ++kc) {
        int k0 = kc * 50;
        for (int idx = t; idx < 64*50; idx += 256) {
            int k = idx % 50, r = idx / 50;
            xs[k*68 + r] = ldin(x, (row0 + r)*100 + k0 + k, isbf);
        }
        for (int idx = t; idx < 50*64; idx += 256) {
            int c = idx & 63, k = idx >> 6;
            wsb[k*68 + c] = Wt[(k0 + k)*256 + c0 + c];
        }
        __syncthreads();
        #pragma unroll 5
        for (int k = 0; k < 50; ++k) {
            float4 av = *(const float4*)&xs[k*68 + 4*ty];
            float4 bv = *(const float4*)&wsb[k*68 + 4*tx];
            float a4[4] = {av.x, av.y, av.z, av.w};
            float b4[4] = {bv.x, bv.y, bv.z, bv.w};
            #pragma unroll
            for (int r = 0; r < 4; ++r)
                #pragma unroll
                for (int c = 0; c < 4; ++c)
                    acc[r][c] = fmaf(a4[r], b4[c], acc[r][c]);
        }
        __syncthreads();
    }
    const float* eb = ws + OFF_ENCB;
    float* U = ws + OFF_U;
    #pragma unroll
    for (int r = 0; r < 4; ++r)
        #pragma unroll
        for (int c = 0; c < 4; ++c) {
            long row = row0 + 4*ty + r;
            int col = c0 + 4*tx + c;
            U[row*256 + col] = acc[r][c] + eb[col];
        }
}

// ---------------- K2a: per-chunk local scan (zero init) -> final states ----------------
// thread = (b, c, h); 32 complex states in registers; no output except final state.
// Final states stored overlaid into this chunk's own H1 rows: plane p=2n (re), 2n+1 (im),
// addr = H1 + chunk_row_base*256 + p*256 + h  (coalesced across h).
__global__ __launch_bounds__(256, 2) void k_scan_local(float* ws)
{
    int bid = blockIdx.x;                 // b*CC + c
    int h = threadIdx.x;
    int base = h * NN;
    float wre[NN], wim[NN], sre[NN], sim[NN];
    #pragma unroll
    for (int n = 0; n < NN; ++n) {
        wre[n] = ws[OFF_WRE + base + n];
        wim[n] = ws[OFF_WIM + base + n];
        sre[n] = 0.0f; sim[n] = 0.0f;
    }
    const float* Up = ws + OFF_U + (long)bid * CH * 256 + h;
    float u = Up[0];
    for (int j = 0; j < CH; ++j) {
        float un = (j + 1 < CH) ? Up[(long)(j + 1) * 256] : 0.0f;
        #pragma unroll
        for (int n = 0; n < NN; ++n) {
            float nr = fmaf(wre[n], sre[n], fmaf(-wim[n], sim[n], u));
            float ni = fmaf(wim[n], sre[n], wre[n] * sim[n]);
            sre[n] = nr; sim[n] = ni;
        }
        u = un;
    }
    float* P = ws + OFF_H1 + (long)bid * CH * 256;
    #pragma unroll
    for (int n = 0; n < NN; ++n) {
        P[(2*n) * 256 + h]     = sre[n];
        P[(2*n + 1) * 256 + h] = sim[n];
    }
}

// ---------------- K2b: chunk-level serial scan: final states -> initial states --------
// thread = (b, h, n). In-place: P[c] := s0_c, where s0_0=0, s0_{c+1}=w^CH*s0_c + S_c.
__global__ __launch_bounds__(256) void k_chunk(float* ws)
{
    int tid = blockIdx.x * 256 + threadIdx.x;   // 131072 threads
    int b = tid >> 13;
    int n = (tid >> 8) & 31;
    int h = tid & 255;
    int i = h * NN + n;
    float wr = ws[OFF_WCHR + i], wi = ws[OFF_WCHI + i];
    float rr = 0.0f, ri = 0.0f;
    for (int c = 0; c < CC; ++c) {
        float* P = ws + OFF_H1 + (long)(b * CC + c) * CH * 256;
        float Sr = P[(2*n) * 256 + h];
        float Si = P[(2*n + 1) * 256 + h];
        P[(2*n) * 256 + h]     = rr;
        P[(2*n + 1) * 256 + h] = ri;
        float nr = fmaf(wr, rr, fmaf(-wi, ri, Sr));
        float ni = fmaf(wr, ri, fmaf(wi, rr, Si));
        rr = nr; ri = ni;
    }
}

// ---------------- K2c: per-chunk full scan with correct init + output fusion ----------
// thread = (b, c, h): y = sum_n Re(k_n s_n); H1 = gelu(y + D*u) + u.
// Reads its own chunk's overlaid init states, then overwrites those rows.
__global__ __launch_bounds__(256, 2) void k_scan_out(float* ws)
{
    int bid = blockIdx.x;                 // b*CC + c
    int h = threadIdx.x;
    int base = h * NN;
    float wre[NN], wim[NN], kre[NN], kim[NN], sre[NN], sim[NN];
    #pragma unroll
    for (int n = 0; n < NN; ++n) {
        wre[n] = ws[OFF_WRE + base + n];
        wim[n] = ws[OFF_WIM + base + n];
        kre[n] = ws[OFF_KRE + base + n];
        kim[n] = ws[OFF_KIM + base + n];
    }
    float D = ws[OFF_DSK + h];
    float* P = ws + OFF_H1 + (long)bid * CH * 256;
    #pragma unroll
    for (int n = 0; n < NN; ++n) {
        sre[n] = P[(2*n) * 256 + h];
        sim[n] = P[(2*n + 1) * 256 + h];
    }
    __syncthreads();                      // all init-state reads done before overwrite
    const float* Up = ws + OFF_U + (long)bid * CH * 256 + h;
    float* Hp = P + h;
    float u = Up[0];
    for (int j = 0; j < CH; ++j) {
        float un = (j + 1 < CH) ? Up[(long)(j + 1) * 256] : 0.0f;
        float acc = 0.0f;
        #pragma unroll
        for (int n = 0; n < NN; ++n) {
            float nr = fmaf(wre[n], sre[n], fmaf(-wim[n], sim[n], u));
            float ni = fmaf(wim[n], sre[n], wre[n] * sim[n]);
            sre[n] = nr; sim[n] = ni;
            acc = fmaf(kre[n], nr, acc);
            acc = fmaf(kim[n], ni, acc);
        }
        float val = fmaf(D, u, acc);
        Hp[(long)j * 256] = gelu_exact(val) + u;
        u = un;
    }
}

// ---------------- K3: LayerNorm over H (in place H1 -> T) ----------------
__global__ __launch_bounds__(256) void k_ln(float* ws)
{
    long row = blockIdx.x;
    float* H1 = ws + OFF_H1 + row * 256;
    int t = threadIdx.x;
    float v = H1[t];
    __shared__ float red[4];
    float s = v;
    s += __shfl_xor(s, 1);  s += __shfl_xor(s, 2);  s += __shfl_xor(s, 4);
    s += __shfl_xor(s, 8);  s += __shfl_xor(s, 16); s += __shfl_xor(s, 32);
    if ((t & 63) == 0) red[t >> 6] = s;
    __syncthreads();
    float mean = (red[0] + red[1] + red[2] + red[3]) * (1.0f/256.0f);
    __syncthreads();
    float d = v - mean;
    float q = d * d;
    q += __shfl_xor(q, 1);  q += __shfl_xor(q, 2);  q += __shfl_xor(q, 4);
    q += __shfl_xor(q, 8);  q += __shfl_xor(q, 16); q += __shfl_xor(q, 32);
    if ((t & 63) == 0) red[t >> 6] = q;
    __syncthreads();
    float var = (red[0] + red[1] + red[2] + red[3]) * (1.0f/256.0f);
    float rs = rsqrtf(var + 1e-5f);
    H1[t] = d * rs * ws[OFF_LNG + t] + ws[OFF_LNB + t];
}

// ---------------- K4: dec1 GEMM + GELU -> G (bf16, reuses U slot) ----------------
__global__ __launch_bounds__(256) void k_dec1(float* ws)
{
    __shared__ __align__(16) float as[64*68];
    __shared__ __align__(16) float bs[64*68];
    int bid = blockIdx.x;            // 1024 row tiles x 8 col tiles
    int rt = bid >> 3, ct = bid & 7;
    long row0 = (long)rt * 64;
    int c0 = ct * 64;
    int t = threadIdx.x, tx = t & 15, ty = t >> 4;
    const float* T  = ws + OFF_H1;
    const float* W1 = ws + OFF_W1T;
    float acc[4][4] = {};
    for (int kc = 0; kc < 4; ++kc) {
        int k0 = kc * 64;
        for (int idx = t; idx < 4096; idx += 256) {
            int k = idx & 63, r = idx >> 6;
            as[k*68 + r] = T[(row0 + r)*256 + k0 + k];
        }
        for (int idx = t; idx < 4096; idx += 256) {
            int c = idx & 63, k = idx >> 6;
            bs[k*68 + c] = W1[(k0 + k)*512 + c0 + c];
        }
        __syncthreads();
        #pragma unroll 8
        for (int k = 0; k < 64; ++k) {
            float4 av = *(const float4*)&as[k*68 + 4*ty];
            float4 bv = *(const float4*)&bs[k*68 + 4*tx];
            float a4[4] = {av.x, av.y, av.z, av.w};
            float b4[4] = {bv.x, bv.y, bv.z, bv.w};
            #pragma unroll
            for (int r = 0; r < 4; ++r)
                #pragma unroll
                for (int c = 0; c < 4; ++c)
                    acc[r][c] = fmaf(a4[r], b4[c], acc[r][c]);
        }
        __syncthreads();
    }
    const float* b1 = ws + OFF_B1;
    __hip_bfloat16* G = (__hip_bfloat16*)(ws + OFF_U);
    #pragma unroll
    for (int r = 0; r < 4; ++r)
        #pragma unroll
        for (int c = 0; c < 4; ++c) {
            long row = row0 + 4*ty + r;
            int col = c0 + 4*tx + c;
            float g = gelu_exact(acc[r][c] + b1[col]);
            G[row*512 + col] = __float2bfloat16(g);
        }
}

// ---------------- K5: dec2 GEMM + bias -> d_out ----------------
__global__ __launch_bounds__(256) void k_dec2(float* ws, void* out, const void* lng)
{
    const int isbf = probe_bf16(lng);
    __shared__ __align__(16) float as[64*68];
    __shared__ __align__(16) float bs[64*132];
    int rt = blockIdx.x;             // 1024 row tiles, single col tile (128 >= 100)
    long row0 = (long)rt * 64;
    int t = threadIdx.x, tx = t & 15, ty = t >> 4;
    const __hip_bfloat16* G = (const __hip_bfloat16*)(ws + OFF_U);
    const float* W2 = ws + OFF_W2T;
    float acc[4][8] = {};
    for (int kc = 0; kc < 8; ++kc) {
        int k0 = kc * 64;
        for (int idx = t; idx < 4096; idx += 256) {
            int k = idx & 63, r = idx >> 6;
            as[k*68 + r] = __bfloat162float(G[(row0 + r)*512 + k0 + k]);
        }
        for (int idx = t; idx < 64*128; idx += 256) {
            int c = idx & 127, k = idx >> 7;
            bs[k*132 + c] = W2[(k0 + k)*128 + c];
        }
        __syncthreads();
        #pragma unroll 4
        for (int k = 0; k < 64; ++k) {
            float4 av = *(const float4*)&as[k*68 + 4*ty];
            float4 b0 = *(const float4*)&bs[k*132 + 8*tx];
            float4 b1v = *(const float4*)&bs[k*132 + 8*tx + 4];
            float a4[4] = {av.x, av.y, av.z, av.w};
            float b8[8] = {b0.x, b0.y, b0.z, b0.w, b1v.x, b1v.y, b1v.z, b1v.w};
            #pragma unroll
            for (int r = 0; r < 4; ++r)
                #pragma unroll
                for (int c = 0; c < 8; ++c)
                    acc[r][c] = fmaf(a4[r], b8[c], acc[r][c]);
        }
        __syncthreads();
    }
    const float* b2 = ws + OFF_B2;
    #pragma unroll
    for (int r = 0; r < 4; ++r)
        #pragma unroll
        for (int c = 0; c < 8; ++c) {
            int col = 8*tx + c;
            if (col < 100) {
                long row = row0 + 4*ty + r;
                stout(out, row*100 + col, acc[r][c] + b2[col], isbf);
            }
        }
}

extern "C" void kernel_launch(void* const* d_in, const int* in_sizes, int n_in,
                              void* d_out, int out_size, void* d_ws, size_t ws_size,
                              hipStream_t stream)
{
    float* ws = (float*)d_ws;
    k_prep<<<512, 256, 0, stream>>>(d_in[1], d_in[2], d_in[3], d_in[4], d_in[5],
                                    d_in[6], d_in[7], d_in[8], d_in[9], d_in[10],
                                    d_in[11], d_in[12], d_in[13], d_in[14],
                                    d_in[15], d_in[16], ws);
    k_enc<<<4096, 256, 0, stream>>>(d_in[0], d_in[11], ws);
    k_scan_local<<<BB*CC, 256, 0, stream>>>(ws);
    k_chunk<<<512, 256, 0, stream>>>(ws);
    k_scan_out<<<BB*CC, 256, 0, stream>>>(ws);
    k_ln<<<65536, 256, 0, stream>>>(ws);
    k_dec1<<<8192, 256, 0, stream>>>(ws);
    k_dec2<<<1024, 256, 0, stream>>>(ws, d_out, d_in[11]);
}

// Round 3
// 489.366 us; speedup vs baseline: 5.4640x; 1.6582x over previous
//
#include <hip/hip_runtime.h>
#include <hip/hip_bf16.h>

// Problem dims
#define BB    16
#define LL    4096
#define DIN   100
#define HD    256
#define NN    32       // complex states per channel
#define DHID  512
#define DOUT  100
#define MROWS (BB*LL)  // 65536
#define CH    128      // scan chunk length
#define CC    32       // chunks per sequence (CH*CC == LL)

// ws layout (float offsets)
#define OFF_WRE   0
#define OFF_WIM   8192
#define OFF_KRE   16384
#define OFF_KIM   24576
#define OFF_WCHR  32768                 // w^CH real
#define OFF_WCHI  40960                 // w^CH imag
#define OFF_WENC  49152                 // [k=100][h=256] fp32
#define OFF_ENCB  74752
#define OFF_DSK   75008
#define OFF_LNG   75264
#define OFF_LNB   75520
#define OFF_B1    75776                 // 512
#define OFF_B2    76288                 // 128 padded
#define OFF_W1B   76416                 // bf16 [j=512][k=256]  (65536 floats of space)
#define OFF_W2B   141952                // bf16 [j=128 pad][k=512] (32768 floats)
#define OFF_U     174720                // U fp32 (B,L,H); after scan: reused as Tb bf16 (LN out)
#define OFF_H1    16951936              // H1 fp32 (B,L,H); after LN: reused as G bf16 (B,L,512)
// total floats = 33729152 (~134.9 MB)

typedef __bf16 bf16x8 __attribute__((ext_vector_type(8)));
typedef float  f32x4  __attribute__((ext_vector_type(4)));

static __device__ __forceinline__ int probe_bf16(const void* lng) {
    return ((const unsigned int*)lng)[0] != 0x3f800000u;
}
static __device__ __forceinline__ float ldin(const void* p, long i, int isbf) {
    return isbf ? __bfloat162float(((const __hip_bfloat16*)p)[i]) : ((const float*)p)[i];
}
static __device__ __forceinline__ void stout(void* p, long i, float v, int isbf) {
    if (isbf) ((__hip_bfloat16*)p)[i] = __float2bfloat16(v);
    else      ((float*)p)[i] = v;
}
static __device__ __forceinline__ unsigned short f2bf(float v) {
    union { float f; unsigned u; } c; c.f = v;
    unsigned r = c.u + 0x7fffu + ((c.u >> 16) & 1u);
    return (unsigned short)(r >> 16);
}
static __device__ __forceinline__ float gelu_exact(float x) {
    return 0.5f * x * (1.0f + erff(x * 0.70710678118654752f));
}

// ---------------- K0: derived SSM params + weight convert ----------------
__global__ __launch_bounds__(256) void k_prep(
    const void* encw, const void* encb, const void* logdt, const void* loga,
    const void* aim, const void* bre, const void* bim, const void* cre,
    const void* cim, const void* dsk, const void* lng, const void* lnb,
    const void* w1, const void* b1, const void* w2, const void* b2, float* ws)
{
    const int isbf = probe_bf16(lng);
    unsigned short* W1B = (unsigned short*)(ws + OFF_W1B);
    unsigned short* W2B = (unsigned short*)(ws + OFF_W2B);
    const int total = 8192 + 25600 + 256*4 + 512 + 128 + 131072 + 65536;
    for (int idx = blockIdx.x * blockDim.x + threadIdx.x; idx < total;
         idx += gridDim.x * blockDim.x) {
        int i = idx;
        if (i < 8192) {
            int h = i >> 5;
            float dt  = expf(ldin(logdt, h, isbf));
            float Are = -expf(ldin(loga, i, isbf));
            float Aim = ldin(aim, i, isbf);
            float er  = expf(dt * Are);
            float sv, cv; sincosf(dt * Aim, &sv, &cv);
            float wre = er * cv, wim = er * sv;
            float Bre = ldin(bre, i, isbf), Bim = ldin(bim, i, isbf);
            float Cre = ldin(cre, i, isbf), Cim = ldin(cim, i, isbf);
            float C0re = Bre*Cre - Bim*Cim;
            float C0im = Bre*Cim + Bim*Cre;
            float inv = 1.0f / (Are*Are + Aim*Aim);
            float nre = wre - 1.0f, nim = wim;
            float Zre = (nre*Are + nim*Aim) * inv;
            float Zim = (nim*Are - nre*Aim) * inv;
            float Cpre = C0re*Zre - C0im*Zim;
            float Cpim = C0re*Zim + C0im*Zre;
            ws[OFF_WRE + i] = wre;  ws[OFF_WIM + i] = wim;
            ws[OFF_KRE + i] = 2.0f * Cpre;  ws[OFF_KIM + i] = -2.0f * Cpim;
            float ar = wre, ai = wim;
            #pragma unroll
            for (int q = 0; q < 7; ++q) {     // w^128
                float nr2 = ar*ar - ai*ai;
                float ni2 = 2.0f*ar*ai;
                ar = nr2; ai = ni2;
            }
            ws[OFF_WCHR + i] = ar;  ws[OFF_WCHI + i] = ai;
        } else if ((i -= 8192) < 25600) {          // enc_w (256,100) -> [k][h] fp32
            int h = i % 256, k = i / 256;
            ws[OFF_WENC + k*256 + h] = ldin(encw, (long)h*100 + k, isbf);
        } else if ((i -= 25600) < 256) {
            ws[OFF_ENCB + i] = ldin(encb, i, isbf);
        } else if ((i -= 256) < 256) {
            ws[OFF_DSK + i] = ldin(dsk, i, isbf);
        } else if ((i -= 256) < 256) {
            ws[OFF_LNG + i] = ldin(lng, i, isbf);
        } else if ((i -= 256) < 256) {
            ws[OFF_LNB + i] = ldin(lnb, i, isbf);
        } else if ((i -= 256) < 512) {
            ws[OFF_B1 + i] = ldin(b1, i, isbf);
        } else if ((i -= 512) < 128) {
            ws[OFF_B2 + i] = (i < 100) ? ldin(b2, i, isbf) : 0.0f;
        } else if ((i -= 128) < 131072) {          // dec1_w (512,256) -> bf16 [j][k]
            W1B[i] = f2bf(ldin(w1, i, isbf));
        } else if ((i -= 131072) < 65536) {        // dec2_w (100,512) -> bf16 [j pad128][k]
            int j = i >> 9, k = i & 511;
            W2B[i] = (j < 100) ? f2bf(ldin(w2, (long)j*512 + k, isbf)) : (unsigned short)0;
        }
    }
}

// ---------------- K1: encoder GEMM  U[M,256] = x[M,100] @ WencT + b ----------------
__global__ __launch_bounds__(256) void k_enc(const void* x, const void* lng, float* ws)
{
    const int isbf = probe_bf16(lng);
    __shared__ __align__(16) float xs[50*68];
    __shared__ __align__(16) float wsb[50*68];
    int bid = blockIdx.x;
    int rt = bid >> 2, ct = bid & 3;
    long row0 = (long)rt * 64;
    int c0 = ct * 64;
    int t = threadIdx.x, tx = t & 15, ty = t >> 4;
    const float* Wt = ws + OFF_WENC;
    float acc[4][4] = {};
    for (int kc = 0; kc < 2; ++kc) {
        int k0 = kc * 50;
        for (int idx = t; idx < 64*50; idx += 256) {
            int k = idx % 50, r = idx / 50;
            xs[k*68 + r] = ldin(x, (row0 + r)*100 + k0 + k, isbf);
        }
        for (int idx = t; idx < 50*64; idx += 256) {
            int c = idx & 63, k = idx >> 6;
            wsb[k*68 + c] = Wt[(k0 + k)*256 + c0 + c];
        }
        __syncthreads();
        #pragma unroll 5
        for (int k = 0; k < 50; ++k) {
            float4 av = *(const float4*)&xs[k*68 + 4*ty];
            float4 bv = *(const float4*)&wsb[k*68 + 4*tx];
            float a4[4] = {av.x, av.y, av.z, av.w};
            float b4[4] = {bv.x, bv.y, bv.z, bv.w};
            #pragma unroll
            for (int r = 0; r < 4; ++r)
                #pragma unroll
                for (int c = 0; c < 4; ++c)
                    acc[r][c] = fmaf(a4[r], b4[c], acc[r][c]);
        }
        __syncthreads();
    }
    const float* eb = ws + OFF_ENCB;
    float* U = ws + OFF_U;
    #pragma unroll
    for (int r = 0; r < 4; ++r)
        #pragma unroll
        for (int c = 0; c < 4; ++c) {
            long row = row0 + 4*ty + r;
            int col = c0 + 4*tx + c;
            U[row*256 + col] = acc[r][c] + eb[col];
        }
}

// ---------------- K2a: per-chunk local scan (zero init) -> final states ----------------
__global__ __launch_bounds__(256, 2) void k_scan_local(float* ws)
{
    int bid = blockIdx.x;                 // b*CC + c
    int h = threadIdx.x;
    int base = h * NN;
    float wre[NN], wim[NN], sre[NN], sim[NN];
    #pragma unroll
    for (int n = 0; n < NN; ++n) {
        wre[n] = ws[OFF_WRE + base + n];
        wim[n] = ws[OFF_WIM + base + n];
        sre[n] = 0.0f; sim[n] = 0.0f;
    }
    const float* Up = ws + OFF_U + (long)bid * CH * 256 + h;
    float u = Up[0];
    for (int j = 0; j < CH; ++j) {
        float un = (j + 1 < CH) ? Up[(long)(j + 1) * 256] : 0.0f;
        #pragma unroll
        for (int n = 0; n < NN; ++n) {
            float nr = fmaf(wre[n], sre[n], fmaf(-wim[n], sim[n], u));
            float ni = fmaf(wim[n], sre[n], wre[n] * sim[n]);
            sre[n] = nr; sim[n] = ni;
        }
        u = un;
    }
    float* P = ws + OFF_H1 + (long)bid * CH * 256;
    #pragma unroll
    for (int n = 0; n < NN; ++n) {
        P[(2*n) * 256 + h]     = sre[n];
        P[(2*n + 1) * 256 + h] = sim[n];
    }
}

// ---------------- K2b: chunk-level serial scan: final -> initial states --------
__global__ __launch_bounds__(256) void k_chunk(float* ws)
{
    int tid = blockIdx.x * 256 + threadIdx.x;   // 131072 threads
    int b = tid >> 13;
    int n = (tid >> 8) & 31;
    int h = tid & 255;
    int i = h * NN + n;
    float wr = ws[OFF_WCHR + i], wi = ws[OFF_WCHI + i];
    float rr = 0.0f, ri = 0.0f;
    for (int c = 0; c < CC; ++c) {
        float* P = ws + OFF_H1 + (long)(b * CC + c) * CH * 256;
        float Sr = P[(2*n) * 256 + h];
        float Si = P[(2*n + 1) * 256 + h];
        P[(2*n) * 256 + h]     = rr;
        P[(2*n + 1) * 256 + h] = ri;
        float nr = fmaf(wr, rr, fmaf(-wi, ri, Sr));
        float ni = fmaf(wr, ri, fmaf(wi, rr, Si));
        rr = nr; ri = ni;
    }
}

// ---------------- K2c: per-chunk full scan + Dskip + GELU + residual ----------
__global__ __launch_bounds__(256, 2) void k_scan_out(float* ws)
{
    int bid = blockIdx.x;                 // b*CC + c
    int h = threadIdx.x;
    int base = h * NN;
    float wre[NN], wim[NN], kre[NN], kim[NN], sre[NN], sim[NN];
    #pragma unroll
    for (int n = 0; n < NN; ++n) {
        wre[n] = ws[OFF_WRE + base + n];
        wim[n] = ws[OFF_WIM + base + n];
        kre[n] = ws[OFF_KRE + base + n];
        kim[n] = ws[OFF_KIM + base + n];
    }
    float D = ws[OFF_DSK + h];
    float* P = ws + OFF_H1 + (long)bid * CH * 256;
    #pragma unroll
    for (int n = 0; n < NN; ++n) {
        sre[n] = P[(2*n) * 256 + h];
        sim[n] = P[(2*n + 1) * 256 + h];
    }
    __syncthreads();                      // all init-state reads done before overwrite
    const float* Up = ws + OFF_U + (long)bid * CH * 256 + h;
    float* Hp = P + h;
    float u = Up[0];
    for (int j = 0; j < CH; ++j) {
        float un = (j + 1 < CH) ? Up[(long)(j + 1) * 256] : 0.0f;
        float acc = 0.0f;
        #pragma unroll
        for (int n = 0; n < NN; ++n) {
            float nr = fmaf(wre[n], sre[n], fmaf(-wim[n], sim[n], u));
            float ni = fmaf(wim[n], sre[n], wre[n] * sim[n]);
            sre[n] = nr; sim[n] = ni;
            acc = fmaf(kre[n], nr, acc);
            acc = fmaf(kim[n], ni, acc);
        }
        float val = fmaf(D, u, acc);
        Hp[(long)j * 256] = gelu_exact(val) + u;
        u = un;
    }
}

// ---------------- K3: LayerNorm (H1 fp32 -> Tb bf16 in retired U slot) ----------------
__global__ __launch_bounds__(256) void k_ln(float* ws)
{
    long row = blockIdx.x;
    const float* H1 = ws + OFF_H1 + row * 256;
    unsigned short* Tb = (unsigned short*)(ws + OFF_U);
    int t = threadIdx.x;
    float v = H1[t];
    __shared__ float red[4];
    float s = v;
    s += __shfl_xor(s, 1);  s += __shfl_xor(s, 2);  s += __shfl_xor(s, 4);
    s += __shfl_xor(s, 8);  s += __shfl_xor(s, 16); s += __shfl_xor(s, 32);
    if ((t & 63) == 0) red[t >> 6] = s;
    __syncthreads();
    float mean = (red[0] + red[1] + red[2] + red[3]) * (1.0f/256.0f);
    __syncthreads();
    float d = v - mean;
    float q = d * d;
    q += __shfl_xor(q, 1);  q += __shfl_xor(q, 2);  q += __shfl_xor(q, 4);
    q += __shfl_xor(q, 8);  q += __shfl_xor(q, 16); q += __shfl_xor(q, 32);
    if ((t & 63) == 0) red[t >> 6] = q;
    __syncthreads();
    float var = (red[0] + red[1] + red[2] + red[3]) * (1.0f/256.0f);
    float rs = rsqrtf(var + 1e-5f);
    Tb[row * 256 + t] = f2bf(d * rs * ws[OFF_LNG + t] + ws[OFF_LNB + t]);
}

// ---------------- K4: dec1 MFMA GEMM + GELU -> G bf16 (retired H1 slot) ----------------
// C[M,512] = Tb[M,256] @ W1B[j][k]^T ; 128x128 tiles, BK=64, mfma 16x16x32 bf16
__global__ __launch_bounds__(256) void k_dec1m(float* ws)
{
    __shared__ __bf16 As[128][72];
    __shared__ __bf16 Bs[128][72];
    const unsigned short* Tb  = (const unsigned short*)(ws + OFF_U);
    const unsigned short* W1B = (const unsigned short*)(ws + OFF_W1B);
    int bid = blockIdx.x;            // 512 row tiles x 4 col tiles
    int rt = bid >> 2, ct = bid & 3;
    long row0 = (long)rt * 128;
    int c0 = ct * 128;
    int t = threadIdx.x;
    int lane = t & 63, wv = t >> 6;
    int wm = (wv & 1) * 64, wn = (wv >> 1) * 64;
    int quad = lane >> 4, mr = lane & 15;
    f32x4 acc[4][4] = {};
    for (int kc = 0; kc < 4; ++kc) {
        int k0 = kc * 64;
        #pragma unroll
        for (int it = 0; it < 4; ++it) {
            int idx = t + it * 256;
            int r = idx >> 3, c8 = (idx & 7) * 8;
            *(float4*)&As[r][c8] = *(const float4*)&Tb[(row0 + r) * 256 + k0 + c8];
            *(float4*)&Bs[r][c8] = *(const float4*)&W1B[(long)(c0 + r) * 256 + k0 + c8];
        }
        __syncthreads();
        #pragma unroll
        for (int ks = 0; ks < 64; ks += 32) {
            bf16x8 af[4], bfr[4];
            #pragma unroll
            for (int i = 0; i < 4; ++i)
                af[i] = *(const bf16x8*)&As[wm + i*16 + mr][ks + quad*8];
            #pragma unroll
            for (int j = 0; j < 4; ++j)
                bfr[j] = *(const bf16x8*)&Bs[wn + j*16 + mr][ks + quad*8];
            #pragma unroll
            for (int i = 0; i < 4; ++i)
                #pragma unroll
                for (int j = 0; j < 4; ++j)
                    acc[i][j] = __builtin_amdgcn_mfma_f32_16x16x32_bf16(af[i], bfr[j], acc[i][j], 0, 0, 0);
        }
        __syncthreads();
    }
    const float* b1 = ws + OFF_B1;
    unsigned short* G = (unsigned short*)(ws + OFF_H1);
    #pragma unroll
    for (int j = 0; j < 4; ++j) {
        int col = c0 + wn + j*16 + mr;
        float bb = b1[col];
        #pragma unroll
        for (int i = 0; i < 4; ++i)
            #pragma unroll
            for (int reg = 0; reg < 4; ++reg) {
                long row = row0 + wm + i*16 + quad*4 + reg;
                G[row * 512 + col] = f2bf(gelu_exact(acc[i][j][reg] + bb));
            }
    }
}

// ---------------- K5: dec2 MFMA GEMM + bias -> d_out ----------------
// C[M,128pad] = G[M,512] @ W2B[j][k]^T ; 128x128 tile (single col tile), BK=64
__global__ __launch_bounds__(256) void k_dec2m(float* ws, void* out, const void* lng)
{
    const int isbf = probe_bf16(lng);
    __shared__ __bf16 As[128][72];
    __shared__ __bf16 Bs[128][72];
    const unsigned short* G   = (const unsigned short*)(ws + OFF_H1);
    const unsigned short* W2B = (const unsigned short*)(ws + OFF_W2B);
    long row0 = (long)blockIdx.x * 128;
    int t = threadIdx.x;
    int lane = t & 63, wv = t >> 6;
    int wm = (wv & 1) * 64, wn = (wv >> 1) * 64;
    int quad = lane >> 4, mr = lane & 15;
    f32x4 acc[4][4] = {};
    for (int kc = 0; kc < 8; ++kc) {
        int k0 = kc * 64;
        #pragma unroll
        for (int it = 0; it < 4; ++it) {
            int idx = t + it * 256;
            int r = idx >> 3, c8 = (idx & 7) * 8;
            *(float4*)&As[r][c8] = *(const float4*)&G[(row0 + r) * 512 + k0 + c8];
            *(float4*)&Bs[r][c8] = *(const float4*)&W2B[(long)r * 512 + k0 + c8];
        }
        __syncthreads();
        #pragma unroll
        for (int ks = 0; ks < 64; ks += 32) {
            bf16x8 af[4], bfr[4];
            #pragma unroll
            for (int i = 0; i < 4; ++i)
                af[i] = *(const bf16x8*)&As[wm + i*16 + mr][ks + quad*8];
            #pragma unroll
            for (int j = 0; j < 4; ++j)
                bfr[j] = *(const bf16x8*)&Bs[wn + j*16 + mr][ks + quad*8];
            #pragma unroll
            for (int i = 0; i < 4; ++i)
                #pragma unroll
                for (int j = 0; j < 4; ++j)
                    acc[i][j] = __builtin_amdgcn_mfma_f32_16x16x32_bf16(af[i], bfr[j], acc[i][j], 0, 0, 0);
        }
        __syncthreads();
    }
    const float* b2 = ws + OFF_B2;
    #pragma unroll
    for (int j = 0; j < 4; ++j) {
        int col = wn + j*16 + mr;
        if (col < 100) {
            float bb = b2[col];
            #pragma unroll
            for (int i = 0; i < 4; ++i)
                #pragma unroll
                for (int reg = 0; reg < 4; ++reg) {
                    long row = row0 + wm + i*16 + quad*4 + reg;
                    stout(out, row * 100 + col, acc[i][j][reg] + bb, isbf);
                }
        }
    }
}

extern "C" void kernel_launch(void* const* d_in, const int* in_sizes, int n_in,
                              void* d_out, int out_size, void* d_ws, size_t ws_size,
                              hipStream_t stream)
{
    float* ws = (float*)d_ws;
    k_prep<<<512, 256, 0, stream>>>(d_in[1], d_in[2], d_in[3], d_in[4], d_in[5],
                                    d_in[6], d_in[7], d_in[8], d_in[9], d_in[10],
                                    d_in[11], d_in[12], d_in[13], d_in[14],
                                    d_in[15], d_in[16], ws);
    k_enc<<<4096, 256, 0, stream>>>(d_in[0], d_in[11], ws);
    k_scan_local<<<BB*CC, 256, 0, stream>>>(ws);
    k_chunk<<<512, 256, 0, stream>>>(ws);
    k_scan_out<<<BB*CC, 256, 0, stream>>>(ws);
    k_ln<<<65536, 256, 0, stream>>>(ws);
    k_dec1m<<<2048, 256, 0, stream>>>(ws);
    k_dec2m<<<512, 256, 0, stream>>>(ws, d_out, d_in[11]);
}